// Round 1
// baseline (276.366 us; speedup 1.0000x reference)
//
#include <hip/hip_runtime.h>
#include <math.h>

#define NROWS (1024 * 4096)   // BATCH * TIMESTEPS = 2^22
#define BLOCKS 2048
#define TPB 256

__global__ void zero_counters(unsigned int* __restrict__ c) {
    if (threadIdx.x < 4) c[threadIdx.x] = 0u;
}

__global__ __launch_bounds__(TPB) void penalty_main(
        const float* __restrict__ x,
        const float* __restrict__ min_,
        const float* __restrict__ scale_,
        unsigned int* __restrict__ counters) {
    const float min2 = min_[2], min3 = min_[3];
    const float sc2  = scale_[2], sc3 = scale_[3];

    const int lane = threadIdx.x & 63;
    const long long T = (long long)BLOCKS * TPB;          // 2^19 threads
    const long long t = (long long)blockIdx.x * TPB + threadIdx.x;

    unsigned int c1 = 0, c2 = 0, c3 = 0, c4 = 0;

    // N divisible by T -> every thread runs exactly NROWS/T iterations,
    // all 64 lanes active at every shuffle.
    for (long long i = t; i < NROWS; i += T) {
        const float2 v = *(const float2*)(x + 8 * i + 2);  // cols 2,3
        const float d = (v.x - min2) / sc2;
        const float a = (v.y - min3) / sc3;

        c1 += !(d >= 0.0f && d <= 252.0f);                 // device penalty
        c2 += (a < 0.0f) || (a > 22.0f);                   // activity penalty
        c4 += (a != 22.0f);                                // activity count

        // transition penalty: need a[i+1]
        float a_next = __shfl_down(a, 1);                  // lane+1's a (same i)
        if (lane == 63) {
            const long long j = i + 1;
            // last row overall has no transition; guarded by cond below.
            a_next = (j < NROWS) ? (x[8 * j + 3] - min3) / sc3 : a;
        }
        const bool cond = (fmodf(a, 2.0f) == 0.0f) && (a < 20.0f)
                          && (i + 1 < NROWS);
        const bool invalid = (a_next != a + 1.0f) && (a_next != 22.0f);
        c3 += (cond && invalid);
    }

    // wave reduction (64 lanes)
    for (int off = 32; off > 0; off >>= 1) {
        c1 += __shfl_down(c1, off);
        c2 += __shfl_down(c2, off);
        c3 += __shfl_down(c3, off);
        c4 += __shfl_down(c4, off);
    }

    __shared__ unsigned int s[4][4];
    const int wave = threadIdx.x >> 6;
    if (lane == 0) {
        s[wave][0] = c1; s[wave][1] = c2; s[wave][2] = c3; s[wave][3] = c4;
    }
    __syncthreads();
    if (threadIdx.x == 0) {
        unsigned int t1 = 0, t2 = 0, t3 = 0, t4 = 0;
        #pragma unroll
        for (int w = 0; w < TPB / 64; ++w) {
            t1 += s[w][0]; t2 += s[w][1]; t3 += s[w][2]; t4 += s[w][3];
        }
        atomicAdd(&counters[0], t1);
        atomicAdd(&counters[1], t2);
        atomicAdd(&counters[2], t3);
        atomicAdd(&counters[3], t4);
    }
}

__global__ void finalize(const unsigned int* __restrict__ c,
                         float* __restrict__ out) {
    const float r = (float)c[0] + (float)c[1] + (float)c[2]
                  + fabsf((float)c[3] - 58.0f);
    out[0] = r;
}

extern "C" void kernel_launch(void* const* d_in, const int* in_sizes, int n_in,
                              void* d_out, int out_size, void* d_ws, size_t ws_size,
                              hipStream_t stream) {
    const float* x   = (const float*)d_in[0];
    const float* mn  = (const float*)d_in[1];
    const float* sc  = (const float*)d_in[2];
    unsigned int* counters = (unsigned int*)d_ws;   // 16 bytes used
    float* out = (float*)d_out;

    zero_counters<<<1, 64, 0, stream>>>(counters);
    penalty_main<<<BLOCKS, TPB, 0, stream>>>(x, mn, sc, counters);
    finalize<<<1, 1, 0, stream>>>(counters, out);
}

// Round 2
// 202.466 us; speedup vs baseline: 1.3650x; 1.3650x over previous
//
#include <hip/hip_runtime.h>
#include <math.h>

#define NROWS (1024 * 4096)        // 2^22 rows
#define BLOCKS 2048
#define TPB 256
#define R 8                        // NROWS / (BLOCKS*TPB), exact
#define NW (TPB / 64)              // waves per block

__global__ __launch_bounds__(TPB) void penalty_main(
        const float* __restrict__ x,
        const float* __restrict__ min_,
        const float* __restrict__ scale_,
        unsigned int* __restrict__ part) {
    const float min2 = min_[2], min3 = min_[3];
    const float sc2  = scale_[2], sc3 = scale_[3];

    const int tid  = threadIdx.x;
    const int lane = tid & 63;
    const int wave = tid >> 6;
    const unsigned T = BLOCKS * TPB;                    // 2^19
    const unsigned t = blockIdx.x * TPB + tid;          // thread's first row

    // ---- phase 1: 8 independent loads in flight ----
    float2 v[R];
    #pragma unroll
    for (int r = 0; r < R; ++r) {
        v[r] = *(const float2*)(x + 8u * (t + (unsigned)r * T) + 2u);
    }

    // ---- phase 2: per-row predicates ----
    float a[R];
    unsigned c1 = 0, c2 = 0, c4 = 0;
    #pragma unroll
    for (int r = 0; r < R; ++r) {
        const float d = (v[r].x - min2) / sc2;
        a[r] = (v[r].y - min3) / sc3;
        c1 += !(d >= 0.0f && d <= 252.0f);
        c2 += (a[r] < 0.0f) || (a[r] > 22.0f);
        c4 += (a[r] != 22.0f);
    }

    // ---- cross-wave handoff: each wave's lane 0 publishes its a[] ----
    __shared__ float sA[NW][R];
    if (lane == 0) {
        #pragma unroll
        for (int r = 0; r < R; ++r) sA[wave][r] = a[r];
    }
    __syncthreads();

    // tid==255: neighbor rows live in the next block -> 8 boundary loads
    float abound[R];
    if (tid == TPB - 1) {
        #pragma unroll
        for (int r = 0; r < R; ++r) {
            const unsigned j = t + (unsigned)r * T + 1u;   // == NROWS only for last row
            abound[r] = (j < NROWS) ? (x[8u * j + 3u] - min3) / sc3 : 0.0f;
        }
    }

    // ---- transition penalty ----
    unsigned c3 = 0;
    #pragma unroll
    for (int r = 0; r < R; ++r) {
        float an = __shfl_down(a[r], 1);
        if (lane == 63) an = (wave < NW - 1) ? sA[wave + 1][r] : abound[r];
        const unsigned i = t + (unsigned)r * T;
        const bool cond = (fmodf(a[r], 2.0f) == 0.0f) && (a[r] < 20.0f)
                          && (i + 1u < NROWS);
        const bool invalid = (an != a[r] + 1.0f) && (an != 22.0f);
        c3 += (cond && invalid);
    }

    // ---- block reduction, no atomics ----
    for (int off = 32; off > 0; off >>= 1) {
        c1 += __shfl_down(c1, off);
        c2 += __shfl_down(c2, off);
        c3 += __shfl_down(c3, off);
        c4 += __shfl_down(c4, off);
    }
    __shared__ unsigned int s[NW][4];
    if (lane == 0) { s[wave][0] = c1; s[wave][1] = c2; s[wave][2] = c3; s[wave][3] = c4; }
    __syncthreads();
    if (tid == 0) {
        unsigned t1 = 0, t2 = 0, t3 = 0, t4 = 0;
        #pragma unroll
        for (int w = 0; w < NW; ++w) {
            t1 += s[w][0]; t2 += s[w][1]; t3 += s[w][2]; t4 += s[w][3];
        }
        unsigned int* p = part + 4u * blockIdx.x;
        p[0] = t1; p[1] = t2; p[2] = t3; p[3] = t4;
    }
}

__global__ __launch_bounds__(TPB) void finalize(
        const unsigned int* __restrict__ part, float* __restrict__ out) {
    const int tid = threadIdx.x;
    unsigned c1 = 0, c2 = 0, c3 = 0, c4 = 0;
    for (int b = tid; b < BLOCKS; b += TPB) {
        const unsigned int* p = part + 4 * b;
        c1 += p[0]; c2 += p[1]; c3 += p[2]; c4 += p[3];
    }
    for (int off = 32; off > 0; off >>= 1) {
        c1 += __shfl_down(c1, off);
        c2 += __shfl_down(c2, off);
        c3 += __shfl_down(c3, off);
        c4 += __shfl_down(c4, off);
    }
    __shared__ unsigned int s[NW][4];
    const int lane = tid & 63, wave = tid >> 6;
    if (lane == 0) { s[wave][0] = c1; s[wave][1] = c2; s[wave][2] = c3; s[wave][3] = c4; }
    __syncthreads();
    if (tid == 0) {
        unsigned t1 = 0, t2 = 0, t3 = 0, t4 = 0;
        #pragma unroll
        for (int w = 0; w < NW; ++w) {
            t1 += s[w][0]; t2 += s[w][1]; t3 += s[w][2]; t4 += s[w][3];
        }
        out[0] = (float)t1 + (float)t2 + (float)t3
               + fabsf((float)t4 - 58.0f);
    }
}

extern "C" void kernel_launch(void* const* d_in, const int* in_sizes, int n_in,
                              void* d_out, int out_size, void* d_ws, size_t ws_size,
                              hipStream_t stream) {
    const float* x  = (const float*)d_in[0];
    const float* mn = (const float*)d_in[1];
    const float* sc = (const float*)d_in[2];
    unsigned int* part = (unsigned int*)d_ws;      // BLOCKS*4 uints = 32 KB
    float* out = (float*)d_out;

    penalty_main<<<BLOCKS, TPB, 0, stream>>>(x, mn, sc, part);
    finalize<<<1, TPB, 0, stream>>>(part, out);
}